// Round 9
// baseline (147.880 us; speedup 1.0000x reference)
//
#include <hip/hip_runtime.h>

#define T_N 1024
#define B_N 512
#define HID 20
#define TB3 (T_N * B_N * 3)   // 1572864
#define MEPAD 1152            // me + 128 zero-pad (kl[d<=0] = 0); serial max idx 1151

typedef float f4v __attribute__((ext_vector_type(4), aligned(4)));

__device__ __forceinline__ float bcast_lane(float v, int l) {
    return __int_as_float(__builtin_amdgcn_readlane(__float_as_int(v), l));
}

// ---------------- Kernel 1: memory MLP, LDS-staged weights (r6 proven) ----------------
__global__ __launch_bounds__(64) void me_mlp_kernel(
    const float* __restrict__ t,
    const float* __restrict__ w1, const float* __restrict__ b1,
    const float* __restrict__ w2, const float* __restrict__ b2,
    const float* __restrict__ w3, const float* __restrict__ b3,
    const float* __restrict__ w4, const float* __restrict__ b4,
    float* __restrict__ me)
{
    __shared__ float sw2[HID * HID], sw3[HID * HID];
    __shared__ float sw1[HID], sb1[HID], sb2[HID], sb3[HID], sw4[HID];
    __shared__ float sb4;
    const int tx = threadIdx.x;

    for (int i = tx; i < HID * HID; i += 64) { sw2[i] = w2[i]; sw3[i] = w3[i]; }
    for (int i = tx; i < HID; i += 64) {
        sw1[i] = w1[i]; sb1[i] = b1[i]; sb2[i] = b2[i];
        sb3[i] = b3[i]; sw4[i] = w4[i];
    }
    if (tx == 0) sb4 = b4[0];
    __syncthreads();

    const int r = blockIdx.x * 64 + tx;
    if (r >= MEPAD) return;
    if (r >= T_N) { me[r] = 0.0f; return; }

    const float x = t[r];
    float h1[HID], h2[HID], h3[HID];
    #pragma unroll
    for (int k = 0; k < HID; ++k) h1[k] = tanhf(fmaf(x, sw1[k], sb1[k]));
    for (int j = 0; j < HID; ++j) {
        float s = sb2[j];
        #pragma unroll
        for (int k = 0; k < HID; ++k) s = fmaf(h1[k], sw2[k * HID + j], s);
        h2[j] = tanhf(s);
    }
    for (int j = 0; j < HID; ++j) {
        float s = sb3[j];
        #pragma unroll
        for (int k = 0; k < HID; ++k) s = fmaf(h2[k], sw3[k * HID + j], s);
        h3[j] = tanhf(s);
    }
    float o = sb4;
    #pragma unroll
    for (int k = 0; k < HID; ++k) o = fmaf(h3[k], sw4[k], o);
    me[r] = 1.0f / (1.0f + expf(-o));
}

// ---------------- Kernel 2: CHUNK=128, two-barrier pipeline, even/odd W pair ----------------
__global__ __launch_bounds__(256, 2) void ode_kernel(
    const float* __restrict__ t,
    const float* __restrict__ y,
    const float* __restrict__ me,
    const float* __restrict__ betap,
    const float* __restrict__ gammap,
    float* __restrict__ out)
{
    const int b    = blockIdx.x;
    const int tx   = threadIdx.x;
    const int lane = tx & 63;
    const int wv   = tx >> 6;
    const int swv  = b & 3;                 // serial wave spread across SIMDs

    __shared__ float Ih[T_N + 64];          // I trajectory (+pad for tail addr overrun)
    __shared__ float Sh[T_N + 64];          // S trajectory
    __shared__ float Hs[4][128];            // per-wave H partials for next chunk

    const float dt  = t[0] - t[1];          // 1/1024, exact
    const float rdt = 1.0f / dt;
    const float bet = betap[0];
    const float gam = gammap[0];
    const float Af  = dt * bet;
    const float Bf  = 1.0f - dt * gam;
    const float D2  = dt * dt;
    const float kl1 = me[T_N - 1];          // kl[1]

    float S = y[3 * b + 0];
    float I = y[3 * b + 1];
    const float Rc = S + I + y[3 * b + 2];

    { // zero Hs (512 floats)
        ((float*)Hs)[tx]       = 0.0f;
        ((float*)Hs)[tx + 256] = 0.0f;
    }
    if (tx == 0) { Ih[0] = I; Sh[0] = S; }
    if (tx < 3) {
        out[3 * b + tx] = y[3 * b + tx];                        // solution row 0
        out[TB3 + (size_t)1023 * B_N * 3 + 3 * b + tx] = 0.0f;  // diff row 1023
    }
    __syncthreads();

    const int rank = ((wv - swv + 4) & 3) - 1;   // helpers: 0..2; serial: -1

    for (int p = 0; p < 8; ++p) {
        const int Js = p * 128;
        const int Jn = Js + 128;
        float h0 = 0.f, h1 = 0.f, h2 = 0.f, h3 = 0.f;   // Hmain hi-half (c=64+lane)
        float l0 = 0.f, l1 = 0.f, l2 = 0.f, l3 = 0.f;   // Hmain lo-half (c=lane)

        if (wv == swv) {
            // ======== SERIAL: 128 Euler steps ========
            float W_e = 0.f, W_o = 0.f;
            #pragma unroll
            for (int w = 0; w < 4; ++w) {
                W_e += Hs[w][2 * lane];
                W_o += Hs[w][2 * lane + 1];
            }
            float pre = bcast_lane(W_e, 0);
            const float A0c = p ? Af : 0.0f;
            const float B0c = p ? Bf : 1.0f;
            const float D0c = p ? D2 : 0.0f;
            float mS_e = S, mI_e = I, mS_o = S, mI_o = I;
            const float* gke = me + (T_N - 2 * lane);   // kl[2l - c] = gke[c]
            const float* gko = gke - 1;                 // kl[2l+1 - c] = gko[c]

#define SSTEP(m, AA, BB, DD, KF, KE, KO)                                  \
            {                                                             \
                const float tot = fmaf((KF), I, pre);                     \
                pre = ((m) & 1)                                           \
                    ? bcast_lane(W_e, (hb + (((m) + 1) >> 1)) & 63)       \
                    : bcast_lane(W_o, hb + ((m) >> 1));                   \
                const float SI = S * I;                                   \
                const float tI = (BB) * I;                                \
                const float u1 = fmaf(-(AA), SI, S);                      \
                I = fmaf((AA), SI, tI);                                   \
                S = fmaf((DD), tot, u1);                                  \
                const int cc = hb + ((m) >> 1);                           \
                if ((m) & 1) { if (lane == cc) { mS_o = S; mI_o = I; } }  \
                else         { if (lane == cc) { mS_e = S; mI_e = I; } }  \
                W_e = fmaf((KE), I, W_e);                                 \
                W_o = fmaf((KO), I, W_o);                                 \
            }
#define SGRP0(AA, BB, DD, KF)                                             \
            SSTEP(0, AA, BB, DD, KF, Le[0].x, Lo[0].x)                    \
            SSTEP(1, Af, Bf, D2, kl1, Le[0].y, Lo[0].y)                   \
            SSTEP(2, Af, Bf, D2, kl1, Le[0].z, Lo[0].z)                   \
            SSTEP(3, Af, Bf, D2, kl1, Le[0].w, Lo[0].w)
#define SGRP(u)                                                           \
            SSTEP(4*(u)+0, Af, Bf, D2, kl1, Le[u].x, Lo[u].x)             \
            SSTEP(4*(u)+1, Af, Bf, D2, kl1, Le[u].y, Lo[u].y)             \
            SSTEP(4*(u)+2, Af, Bf, D2, kl1, Le[u].z, Lo[u].z)             \
            SSTEP(4*(u)+3, Af, Bf, D2, kl1, Le[u].w, Lo[u].w)

            #pragma unroll 1
            for (int s4 = 0; s4 < 4; ++s4) {
                f4v Le[8], Lo[8];
                #pragma unroll
                for (int u = 0; u < 8; ++u) {
                    Le[u] = *(const f4v*)(gke + 32 * s4 + 4 * u);
                    Lo[u] = *(const f4v*)(gko + 32 * s4 + 4 * u);
                }
                const int   hb  = 16 * s4;
                const float kf0 = (s4 == 0) ? 0.0f : kl1;  // chunk-start: W-init complete
                const float Am  = (s4 == 0) ? A0c : Af;
                const float Bm  = (s4 == 0) ? B0c : Bf;
                const float Dm  = (s4 == 0) ? D0c : D2;
                SGRP0(Am, Bm, Dm, kf0)
                SGRP(1) SGRP(2) SGRP(3)
                SGRP(4) SGRP(5) SGRP(6) SGRP(7)
            }
#undef SGRP
#undef SGRP0
#undef SSTEP

            // publish chunk p trajectory: lane l holds steps 2l, 2l+1
            Ih[Js + 2 * lane]     = mI_e;
            Ih[Js + 2 * lane + 1] = mI_o;
            Sh[Js + 2 * lane]     = mS_e;
            Sh[Js + 2 * lane + 1] = mS_o;
        } else {
            // ======== HELPERS: store chunk p-1 + Hmain(p+1) ========
            if (p >= 1) {
                const int j0 = Js - 128;
                if (rank == 0) {
                    #pragma unroll
                    for (int h = 0; h < 2; ++h) {
                        const int j = j0 + 64 * h + lane;
                        const float s1 = Sh[j], i1 = Ih[j];
                        float* so = out + (size_t)j * (B_N * 3) + 3 * b;
                        so[0] = s1; so[1] = i1; so[2] = Rc - s1 - i1;
                    }
                } else if (rank == 1) {
                    #pragma unroll
                    for (int h = 0; h < 2; ++h) {
                        const int j = j0 + 64 * h + lane;
                        if (j >= 1) {
                            const float dS = (Sh[j] - Sh[j - 1]) * rdt;
                            const float dI = (Ih[j] - Ih[j - 1]) * rdt;
                            float* df = out + TB3 + (size_t)(j - 1) * (B_N * 3) + 3 * b;
                            df[0] = dS; df[1] = dI; df[2] = -(dS + dI);
                        }
                    }
                }
            }
            if (p < 7) {
                // Hmain(p+1): i < 128p, 64-wide segments, 3-wave round-robin
                for (int bb = rank; bb < 2 * p; bb += 3) {
                    const int i0 = 64 * bb;
                    const float ihv = Ih[i0 + lane];
                    const float* bh = me + (T_N - Jn - 64 - lane + i0);  // hi stream; lo = bh+64
                    f4v L[32];
                    #pragma unroll
                    for (int u = 0; u < 32; ++u) L[u] = *(const f4v*)(bh + 4 * u);
                    #pragma unroll
                    for (int g = 0; g < 8; ++g) {
                        float r0 = bcast_lane(ihv, 8 * g + 0);
                        float r1 = bcast_lane(ihv, 8 * g + 1);
                        float r2 = bcast_lane(ihv, 8 * g + 2);
                        float r3 = bcast_lane(ihv, 8 * g + 3);
                        float r4 = bcast_lane(ihv, 8 * g + 4);
                        float r5 = bcast_lane(ihv, 8 * g + 5);
                        float r6 = bcast_lane(ihv, 8 * g + 6);
                        float r7 = bcast_lane(ihv, 8 * g + 7);
                        const f4v Ha = L[2 * g], Hb = L[2 * g + 1];
                        const f4v La = L[16 + 2 * g], Lb = L[16 + 2 * g + 1];
                        h0 = fmaf(r0, Ha.x, h0); h1 = fmaf(r1, Ha.y, h1);
                        h2 = fmaf(r2, Ha.z, h2); h3 = fmaf(r3, Ha.w, h3);
                        l0 = fmaf(r0, La.x, l0); l1 = fmaf(r1, La.y, l1);
                        l2 = fmaf(r2, La.z, l2); l3 = fmaf(r3, La.w, l3);
                        h0 = fmaf(r4, Hb.x, h0); h1 = fmaf(r5, Hb.y, h1);
                        h2 = fmaf(r6, Hb.z, h2); h3 = fmaf(r7, Hb.w, h3);
                        l0 = fmaf(r4, Lb.x, l0); l1 = fmaf(r5, Lb.y, l1);
                        l2 = fmaf(r6, Lb.z, l2); l3 = fmaf(r7, Lb.w, l3);
                    }
                }
            }
        }
        __syncthreads();   // barrier A: chunk p published; Hmain done

        if (p < 7) {
            // ======== tail: i in [Js, Js+128), 32 per wave, all 4 waves ========
            const int i0t = Js + 32 * wv;
            const float ihv = Ih[i0t + lane];                 // lanes 0..31 used
            const float* blo = me + (T_N - Jn - lane + i0t);  // c = lane
            const float* bhi = blo - 64;                      // c = 64 + lane
            f4v Tl[8], Th[8];
            #pragma unroll
            for (int u = 0; u < 8; ++u) {
                Tl[u] = *(const f4v*)(blo + 4 * u);
                Th[u] = *(const f4v*)(bhi + 4 * u);
            }
            float tl0 = 0.f, tl1 = 0.f, tl2 = 0.f, tl3 = 0.f;
            float th0 = 0.f, th1 = 0.f, th2 = 0.f, th3 = 0.f;
            #pragma unroll
            for (int g = 0; g < 4; ++g) {
                float r0 = bcast_lane(ihv, 8 * g + 0);
                float r1 = bcast_lane(ihv, 8 * g + 1);
                float r2 = bcast_lane(ihv, 8 * g + 2);
                float r3 = bcast_lane(ihv, 8 * g + 3);
                float r4 = bcast_lane(ihv, 8 * g + 4);
                float r5 = bcast_lane(ihv, 8 * g + 5);
                float r6 = bcast_lane(ihv, 8 * g + 6);
                float r7 = bcast_lane(ihv, 8 * g + 7);
                const f4v La = Tl[2 * g], Lb = Tl[2 * g + 1];
                const f4v Ha = Th[2 * g], Hb = Th[2 * g + 1];
                tl0 = fmaf(r0, La.x, tl0); tl1 = fmaf(r1, La.y, tl1);
                tl2 = fmaf(r2, La.z, tl2); tl3 = fmaf(r3, La.w, tl3);
                th0 = fmaf(r0, Ha.x, th0); th1 = fmaf(r1, Ha.y, th1);
                th2 = fmaf(r2, Ha.z, th2); th3 = fmaf(r3, Ha.w, th3);
                tl0 = fmaf(r4, Lb.x, tl0); tl1 = fmaf(r5, Lb.y, tl1);
                tl2 = fmaf(r6, Lb.z, tl2); tl3 = fmaf(r7, Lb.w, tl3);
                th0 = fmaf(r4, Hb.x, th0); th1 = fmaf(r5, Hb.y, th1);
                th2 = fmaf(r6, Hb.z, th2); th3 = fmaf(r7, Hb.w, th3);
            }
            // serial wave's hX/lX are zero -> uniform write
            Hs[wv][lane]      = ((l0 + l1) + (l2 + l3)) + ((tl0 + tl1) + (tl2 + tl3));
            Hs[wv][64 + lane] = ((h0 + h1) + (h2 + h3)) + ((th0 + th1) + (th2 + th3));
        }
        __syncthreads();   // barrier B: Hs ready for chunk p+1
    }

    // ======== epilogue: chunk 7 rows (896..1023; diff 895..1022) ========
    if (rank == 0) {
        #pragma unroll
        for (int h = 0; h < 2; ++h) {
            const int j = 896 + 64 * h + lane;
            const float s1 = Sh[j], i1 = Ih[j];
            float* so = out + (size_t)j * (B_N * 3) + 3 * b;
            so[0] = s1; so[1] = i1; so[2] = Rc - s1 - i1;
        }
    } else if (rank == 1) {
        #pragma unroll
        for (int h = 0; h < 2; ++h) {
            const int j = 896 + 64 * h + lane;
            const float dS = (Sh[j] - Sh[j - 1]) * rdt;
            const float dI = (Ih[j] - Ih[j - 1]) * rdt;
            float* df = out + TB3 + (size_t)(j - 1) * (B_N * 3) + 3 * b;
            df[0] = dS; df[1] = dI; df[2] = -(dS + dI);
        }
    }
}

// ---------------- launcher ----------------
extern "C" void kernel_launch(void* const* d_in, const int* in_sizes, int n_in,
                              void* d_out, int out_size, void* d_ws, size_t ws_size,
                              hipStream_t stream)
{
    const float* t   = (const float*)d_in[0];
    const float* y   = (const float*)d_in[1];
    const float* w1  = (const float*)d_in[2];
    const float* b1  = (const float*)d_in[3];
    const float* w2  = (const float*)d_in[4];
    const float* b2  = (const float*)d_in[5];
    const float* w3  = (const float*)d_in[6];
    const float* b3  = (const float*)d_in[7];
    const float* w4  = (const float*)d_in[8];
    const float* b4  = (const float*)d_in[9];
    const float* bet = (const float*)d_in[10];
    const float* gam = (const float*)d_in[11];
    float* out = (float*)d_out;
    float* me  = (float*)d_ws;   // 1152 floats of scratch (me + zero pad)

    me_mlp_kernel<<<dim3(MEPAD / 64), dim3(64), 0, stream>>>(
        t, w1, b1, w2, b2, w3, b3, w4, b4, me);
    ode_kernel<<<dim3(B_N), dim3(256), 0, stream>>>(t, y, me, bet, gam, out);
}